// Round 2
// baseline (588.097 us; speedup 1.0000x reference)
//
#include <hip/hip_runtime.h>

typedef unsigned int u32;
typedef unsigned short u16;
typedef unsigned long long u64;

using f32x4 = __attribute__((ext_vector_type(4))) float;
using bf16x8 = __attribute__((ext_vector_type(8))) short;

#define BN_EPS 1e-5f

__device__ __forceinline__ float bflo(u32 u) {
    union { u32 u; float f; } v; v.u = u << 16; return v.f;
}
__device__ __forceinline__ float bfhi(u32 u) {
    union { u32 u; float f; } v; v.u = u & 0xffff0000u; return v.f;
}
__device__ __forceinline__ u32 f2bf(float f) {   // round-to-nearest-even bf16 bits
    union { float f; u32 u; } v; v.f = f;
    return (v.u + 0x7fffu + ((v.u >> 16) & 1u)) >> 16;
}

// ---------------- edge dtype detect + convert ----------------
__global__ void detect_k(const void* ei, int* flag, int nnode) {
    const u64* p = (const u64*)ei;
    int lane = threadIdx.x & 63;
    u64 v = p[lane];
    int ok = (v < (u64)nnode);
    int all64 = __all(ok);
    if (threadIdx.x == 0) *flag = all64 ? 1 : 0;
}

__global__ void convert_edges_k(const void* ei, int* __restrict__ src, int* __restrict__ dst,
                                const int* __restrict__ flag, int E) {
    int is64 = *flag;
    int i = blockIdx.x * blockDim.x + threadIdx.x;
    int stride = gridDim.x * blockDim.x;
    if (is64) {
        const long long* p = (const long long*)ei;
        for (; i < E; i += stride) { src[i] = (int)p[i]; dst[i] = (int)p[E + i]; }
    } else {
        const int* p = (const int*)ei;
        for (; i < E; i += stride) { src[i] = p[i]; dst[i] = p[E + i]; }
    }
}

// ---------------- degree / dinv ----------------
__global__ void deg_count_k(const int* __restrict__ dst, int* __restrict__ degi, int E) {
    int i = blockIdx.x * blockDim.x + threadIdx.x;
    int stride = gridDim.x * blockDim.x;
    for (; i < E; i += stride) atomicAdd(&degi[dst[i]], 1);
}

__global__ void dinv_k(const int* __restrict__ degi, float* __restrict__ dinv, int n) {
    int i = blockIdx.x * blockDim.x + threadIdx.x;
    int stride = gridDim.x * blockDim.x;
    for (; i < n; i += stride) dinv[i] = rsqrtf((float)(degi[i] + 1)); // +1 self-loop
}

// ---------------- hierarchical exclusive scan (row_ptr) ----------------
__global__ void block_sum_k(const int* __restrict__ counts, int* __restrict__ bsum, int n) {
    __shared__ int red[4];
    int idx = blockIdx.x * 256 + threadIdx.x;
    int v = (idx < n) ? counts[idx] : 0;
#pragma unroll
    for (int m = 32; m >= 1; m >>= 1) v += __shfl_xor(v, m);
    int lane = threadIdx.x & 63, w = threadIdx.x >> 6;
    if (lane == 0) red[w] = v;
    __syncthreads();
    if (threadIdx.x == 0) bsum[blockIdx.x] = red[0] + red[1] + red[2] + red[3];
}

__global__ void scan_bsum_k(int* bsum, int nb) { // 1 block, 256 thr, nb<=256
    __shared__ int sd[256];
    int t = threadIdx.x;
    int v = (t < nb) ? bsum[t] : 0;
    sd[t] = v; __syncthreads();
    for (int off = 1; off < 256; off <<= 1) {
        int u = (t >= off) ? sd[t - off] : 0;
        __syncthreads();
        sd[t] += u;
        __syncthreads();
    }
    if (t < nb) bsum[t] = sd[t] - v; // exclusive
}

__global__ void block_scan_k(const int* __restrict__ counts, const int* __restrict__ bsum,
                             int* __restrict__ rp, int n) {
    __shared__ int sd[256];
    int t = threadIdx.x;
    int idx = blockIdx.x * 256 + t;
    int v = (idx < n) ? counts[idx] : 0;
    sd[t] = v; __syncthreads();
    for (int off = 1; off < 256; off <<= 1) {
        int u = (t >= off) ? sd[t - off] : 0;
        __syncthreads();
        sd[t] += u;
        __syncthreads();
    }
    if (idx < n) rp[idx + 1] = bsum[blockIdx.x] + sd[t];
    if (blockIdx.x == 0 && t == 0) rp[0] = 0;
}

__global__ void csr_fill_k(const int* __restrict__ src, const int* __restrict__ dst,
                           const int* __restrict__ rp, int* __restrict__ fill,
                           int* __restrict__ cs, int E) {
    int i = blockIdx.x * blockDim.x + threadIdx.x;
    int stride = gridDim.x * blockDim.x;
    for (; i < E; i += stride) {
        int d = dst[i];
        int pos = atomicAdd(&fill[d], 1);
        cs[rp[d] + pos] = src[i];
    }
}

// ---------------- conversions ----------------
__global__ void f32_to_bf16_k(const float* __restrict__ in, u16* __restrict__ out, int nquads) {
    int i = blockIdx.x * blockDim.x + threadIdx.x;
    int stride = gridDim.x * blockDim.x;
    for (; i < nquads; i += stride) {
        float4 v = ((const float4*)in)[i];
        u32 lo = f2bf(v.x) | (f2bf(v.y) << 16);
        u32 hi = f2bf(v.z) | (f2bf(v.w) << 16);
        ((uint2*)out)[i] = make_uint2(lo, hi);
    }
}

__global__ void transpose_w_k(const float* __restrict__ W, u16* __restrict__ Wt,
                              int din, int dout) {
    int i = blockIdx.x * blockDim.x + threadIdx.x;
    int total = din * dout;
    if (i < total) {
        int r = i / dout, c = i % dout;
        Wt[(size_t)c * din + r] = (u16)f2bf(W[i]);
    }
}

// ---------------- GCN aggregation: out[v] = dinv[v]*(sum_e dinv[src]*h[src]) + dinv[v]^2*h[v]
template <int DIN>
__global__ __launch_bounds__(256) void aggregate_k(
    const u16* __restrict__ H, u16* __restrict__ O,
    const float* __restrict__ dinv, const int* __restrict__ rp,
    const int* __restrict__ cs, int n)
{
    constexpr int U = DIN / 128; // u32 words per lane (1 or 2)
    int node = blockIdx.x * 4 + (threadIdx.x >> 6);
    if (node >= n) return;
    int lane = threadIdx.x & 63;
    const u32* Hu = (const u32*)H;
    float dv = dinv[node];
    float acc[2 * U];
    {
        const u32* row = Hu + (size_t)node * (DIN / 2);
#pragma unroll
        for (int j = 0; j < U; ++j) {
            u32 w = row[lane * U + j];
            acc[2 * j]     = dv * bflo(w);
            acc[2 * j + 1] = dv * bfhi(w);
        }
    }
    int e0 = rp[node], e1 = rp[node + 1];
    for (int e = e0; e < e1; ++e) {
        int s = cs[e];
        float w = dinv[s];
        const u32* row = Hu + (size_t)s * (DIN / 2);
#pragma unroll
        for (int j = 0; j < U; ++j) {
            u32 xx = row[lane * U + j];
            acc[2 * j]     = fmaf(w, bflo(xx), acc[2 * j]);
            acc[2 * j + 1] = fmaf(w, bfhi(xx), acc[2 * j + 1]);
        }
    }
    u32* orow = (u32*)O + (size_t)node * (DIN / 2);
#pragma unroll
    for (int j = 0; j < U; ++j) {
        float x0 = acc[2 * j] * dv, x1 = acc[2 * j + 1] * dv;
        orow[lane * U + j] = f2bf(x0) | (f2bf(x1) << 16);
    }
}

// ---------------- bf16 MFMA GEMM: out[M][256] = A[M][K] * Bt[256][K]^T + bias
// Fused colsum/colsumsq -> per-block partials (no global atomics).
// part layout: part[bx][ y*256 + col_local*2 + {0=s,1=q} ]
template <int K, int OUTB>
__global__ __launch_bounds__(256) void gemm_bf16(
    const u16* __restrict__ A, const u16* __restrict__ Bt,
    const float* __restrict__ bias, void* __restrict__ outp,
    float* __restrict__ part, int M)
{
    // LDS layout [k_hi=4][dim=128][k_lo=8] bf16 — conflict-free ds_read_b128,
    // linear-compatible with global_load_lds (chunk c: dim=c&127, k_hi=c>>7)
    __shared__ __align__(16) u16 lA[4096];
    __shared__ __align__(16) u16 lB[4096];
    __shared__ float red[256]; // [col_local 128][2]
    const int tid = threadIdx.x;
    const int lane = tid & 63;
    const int wid = tid >> 6;
    const int wm = wid >> 1, wn = wid & 1;
    const int l15 = lane & 15, khi = lane >> 4;
    const int row0 = blockIdx.x * 128;
    const int col0 = blockIdx.y * 128;

    f32x4 acc[4][4];
#pragma unroll
    for (int i = 0; i < 4; ++i)
#pragma unroll
        for (int j = 0; j < 4; ++j)
            acc[i][j] = (f32x4){0.f, 0.f, 0.f, 0.f};

    if (tid < 256) red[tid] = 0.f;

    for (int k0 = 0; k0 < K; k0 += 32) {
#pragma unroll
        for (int t = 0; t < 2; ++t) {
            int c = t * 256 + wid * 64 + lane;
            int r = c & 127, kh = c >> 7;
            int ar = row0 + r; if (ar > M - 1) ar = M - 1;
            const u16* ga = A + (size_t)ar * K + k0 + kh * 8;
            u16* la = &lA[(t * 256 + wid * 64) * 8];
            __builtin_amdgcn_global_load_lds(
                (const __attribute__((address_space(1))) void*)ga,
                (__attribute__((address_space(3))) void*)la, 16, 0, 0);
            const u16* gb = Bt + (size_t)(col0 + r) * K + k0 + kh * 8;
            u16* lb = &lB[(t * 256 + wid * 64) * 8];
            __builtin_amdgcn_global_load_lds(
                (const __attribute__((address_space(1))) void*)gb,
                (__attribute__((address_space(3))) void*)lb, 16, 0, 0);
        }
        __syncthreads();
        bf16x8 afr[4], bfr[4];
#pragma unroll
        for (int mi = 0; mi < 4; ++mi)
            afr[mi] = *(const bf16x8*)&lA[khi * 1024 + (wm * 64 + mi * 16 + l15) * 8];
#pragma unroll
        for (int nj = 0; nj < 4; ++nj)
            bfr[nj] = *(const bf16x8*)&lB[khi * 1024 + (wn * 64 + nj * 16 + l15) * 8];
#pragma unroll
        for (int mi = 0; mi < 4; ++mi)
#pragma unroll
            for (int nj = 0; nj < 4; ++nj)
                acc[mi][nj] = __builtin_amdgcn_mfma_f32_16x16x32_bf16(
                    afr[mi], bfr[nj], acc[mi][nj], 0, 0, 0);
        __syncthreads();
    }

#pragma unroll
    for (int mi = 0; mi < 4; ++mi) {
#pragma unroll
        for (int nj = 0; nj < 4; ++nj) {
            int coll = wn * 64 + nj * 16 + l15;
            int colg = col0 + coll;
            float bsv = bias[colg];
            float s = 0.f, q = 0.f;
#pragma unroll
            for (int i = 0; i < 4; ++i) {
                int rowg = row0 + wm * 64 + mi * 16 + khi * 4 + i;
                if (rowg < M) {
                    float v = acc[mi][nj][i] + bsv;
                    if (OUTB) ((u16*)outp)[(size_t)rowg * 256 + colg] = (u16)f2bf(v);
                    else      ((float*)outp)[(size_t)rowg * 256 + colg] = v;
                    s += v; q += v * v;
                }
            }
            s += __shfl_xor(s, 16); s += __shfl_xor(s, 32);
            q += __shfl_xor(q, 16); q += __shfl_xor(q, 32);
            if (lane < 16) {
                atomicAdd(&red[coll * 2], s);
                atomicAdd(&red[coll * 2 + 1], q);
            }
        }
    }
    __syncthreads();
    if (tid < 256)
        part[(size_t)blockIdx.x * 512 + blockIdx.y * 256 + tid] = red[tid];
}

// ---------------- BN stats (reduce partials) ----------------
__global__ void bn_stats_k(const float* __restrict__ part, const float* __restrict__ gamma,
                           const float* __restrict__ beta, float* __restrict__ ss,
                           int nbx, int M) {
    int c = threadIdx.x; // 256
    int base = (c >> 7) * 256 + (c & 127) * 2;
    float s = 0.f, q = 0.f;
    for (int bx = 0; bx < nbx; ++bx) {
        s += part[(size_t)bx * 512 + base];
        q += part[(size_t)bx * 512 + base + 1];
    }
    float mean = s / (float)M;
    float var = q / (float)M - mean * mean;
    var = fmaxf(var, 0.f);
    float sc = gamma[c] * rsqrtf(var + BN_EPS);
    ss[c] = sc;
    ss[256 + c] = beta[c] - mean * sc;
}

// ---------------- BN apply + PReLU ----------------
template <int INB, int OUTB> // bf16 flags for input/output
__global__ void bn_prelu_k(const void* __restrict__ in, void* __restrict__ outp,
                           const float* __restrict__ ss,
                           const float* __restrict__ aptr, int nquads) {
    float a = aptr[0];
    int i = blockIdx.x * blockDim.x + threadIdx.x;
    int stride = gridDim.x * blockDim.x;
    for (; i < nquads; i += stride) {
        float v0, v1, v2, v3;
        if (INB) {
            uint2 u = ((const uint2*)in)[i];
            v0 = bflo(u.x); v1 = bfhi(u.x); v2 = bflo(u.y); v3 = bfhi(u.y);
        } else {
            float4 v = ((const float4*)in)[i];
            v0 = v.x; v1 = v.y; v2 = v.z; v3 = v.w;
        }
        int c0 = (i * 4) & 255;
        float r0 = v0 * ss[c0 + 0] + ss[256 + c0 + 0];
        float r1 = v1 * ss[c0 + 1] + ss[256 + c0 + 1];
        float r2 = v2 * ss[c0 + 2] + ss[256 + c0 + 2];
        float r3 = v3 * ss[c0 + 3] + ss[256 + c0 + 3];
        r0 = r0 > 0.f ? r0 : a * r0;
        r1 = r1 > 0.f ? r1 : a * r1;
        r2 = r2 > 0.f ? r2 : a * r2;
        r3 = r3 > 0.f ? r3 : a * r3;
        if (OUTB) {
            u32 lo = f2bf(r0) | (f2bf(r1) << 16);
            u32 hi = f2bf(r2) | (f2bf(r3) << 16);
            ((uint2*)outp)[i] = make_uint2(lo, hi);
        } else {
            ((float4*)outp)[i] = make_float4(r0, r1, r2, r3);
        }
    }
}

extern "C" void kernel_launch(void* const* d_in, const int* in_sizes, int n_in,
                              void* d_out, int out_size, void* d_ws, size_t ws_size,
                              hipStream_t stream) {
    const float* x   = (const float*)d_in[0];
    const void*  ei  = d_in[1];
    const float* W0  = (const float*)d_in[2];
    const float* b0  = (const float*)d_in[3];
    const float* g0  = (const float*)d_in[4];
    const float* be0 = (const float*)d_in[5];
    const float* a0  = (const float*)d_in[6];
    const float* W1  = (const float*)d_in[7];
    const float* b1  = (const float*)d_in[8];
    const float* g1  = (const float*)d_in[9];
    const float* be1 = (const float*)d_in[10];
    const float* a1  = (const float*)d_in[11];
    float* out = (float*)d_out;

    const int n = in_sizes[0] / 128;
    const int E = in_sizes[1] / 2;
    const int nbx = (n + 127) / 128;

    char* ws = (char*)d_ws;
    size_t off = 0;
    auto alloc = [&](size_t bytes) {
        size_t r = off; off += (bytes + 255) & ~(size_t)255; return r;
    };
    size_t o_src  = alloc((size_t)E * 4);
    size_t o_dst  = alloc((size_t)E * 4);
    size_t o_deg  = alloc((size_t)n * 4);
    size_t o_fill = alloc((size_t)n * 4);
    size_t o_rp   = alloc((size_t)(n + 1) * 4);
    size_t o_bsum = alloc(4096);
    size_t o_flag = alloc(256);
    size_t o_dinv = alloc((size_t)n * 4);
    size_t o_csr  = alloc((size_t)E * 4);
    size_t o_part = alloc((size_t)nbx * 512 * 4);
    size_t o_ss   = alloc(2048);
    size_t o_wt0  = alloc(256 * 128 * 2);
    size_t o_wt1  = alloc(256 * 256 * 2);
    size_t o_xh   = alloc((size_t)n * 128 * 2);
    size_t o_agg0 = alloc((size_t)n * 128 * 2);
    size_t o_y0   = alloc((size_t)n * 256 * 2);
    size_t o_agg1 = o_xh; // overlay: xh+agg0 are dead by the time agg1 is written

    int*   src32 = (int*)(ws + o_src);
    int*   dst32 = (int*)(ws + o_dst);
    int*   degi  = (int*)(ws + o_deg);
    int*   fill  = (int*)(ws + o_fill);
    int*   rp    = (int*)(ws + o_rp);
    int*   bsum  = (int*)(ws + o_bsum);
    int*   flag  = (int*)(ws + o_flag);
    float* dinv  = (float*)(ws + o_dinv);
    int*   csr   = (int*)(ws + o_csr);
    float* part  = (float*)(ws + o_part);
    float* ssbuf = (float*)(ws + o_ss);
    u16*   wt0   = (u16*)(ws + o_wt0);
    u16*   wt1   = (u16*)(ws + o_wt1);
    u16*   xh    = (u16*)(ws + o_xh);
    u16*   agg0  = (u16*)(ws + o_agg0);
    u16*   y0    = (u16*)(ws + o_y0);
    u16*   agg1  = (u16*)(ws + o_agg1);

    hipMemsetAsync(ws + o_deg, 0, (size_t)n * 4, stream);
    hipMemsetAsync(ws + o_fill, 0, (size_t)n * 4, stream);

    const int gE = (E + 255) / 256 < 4096 ? (E + 255) / 256 : 4096;
    const int gN = (n + 255) / 256; // 196 for n=50000 (fits single-block scan of bsum)

    detect_k<<<1, 64, 0, stream>>>(ei, flag, n);
    convert_edges_k<<<gE, 256, 0, stream>>>(ei, src32, dst32, flag, E);
    deg_count_k<<<gE, 256, 0, stream>>>(dst32, degi, E);
    dinv_k<<<gN, 256, 0, stream>>>(degi, dinv, n);
    block_sum_k<<<gN, 256, 0, stream>>>(degi, bsum, n);
    scan_bsum_k<<<1, 256, 0, stream>>>(bsum, gN);
    block_scan_k<<<gN, 256, 0, stream>>>(degi, bsum, rp, n);
    csr_fill_k<<<gE, 256, 0, stream>>>(src32, dst32, rp, fill, csr, E);

    f32_to_bf16_k<<<4096, 256, 0, stream>>>(x, xh, n * 128 / 4);
    transpose_w_k<<<(128 * 256 + 255) / 256, 256, 0, stream>>>(W0, wt0, 128, 256);
    transpose_w_k<<<(256 * 256 + 255) / 256, 256, 0, stream>>>(W1, wt1, 256, 256);

    const dim3 ggrid(nbx, 2);

    // ---- layer 0 ----  (pre-BN output as bf16 into d_out scratch)
    aggregate_k<128><<<(n + 3) / 4, 256, 0, stream>>>(xh, agg0, dinv, rp, csr, n);
    gemm_bf16<128, 1><<<ggrid, 256, 0, stream>>>(agg0, wt0, b0, d_out, part, n);
    bn_stats_k<<<1, 256, 0, stream>>>(part, g0, be0, ssbuf, nbx, n);
    bn_prelu_k<1, 1><<<4096, 256, 0, stream>>>(d_out, y0, ssbuf, a0, n * 256 / 4);

    // ---- layer 1 ----  (f32 into d_out, BN+PReLU in place)
    aggregate_k<256><<<(n + 3) / 4, 256, 0, stream>>>(y0, agg1, dinv, rp, csr, n);
    gemm_bf16<256, 0><<<ggrid, 256, 0, stream>>>(agg1, wt1, b1, d_out, part, n);
    bn_stats_k<<<1, 256, 0, stream>>>(part, g1, be1, ssbuf, nbx, n);
    bn_prelu_k<0, 0><<<4096, 256, 0, stream>>>(out, out, ssbuf, a1, n * 256 / 4);
}

// Round 3
// 391.774 us; speedup vs baseline: 1.5011x; 1.5011x over previous
//
#include <hip/hip_runtime.h>

typedef unsigned int u32;
typedef unsigned short u16;
typedef unsigned long long u64;

using f32x4 = __attribute__((ext_vector_type(4))) float;
using bf16x8 = __attribute__((ext_vector_type(8))) short;

#define BN_EPS 1e-5f

__device__ __forceinline__ float bflo(u32 u) {
    union { u32 u; float f; } v; v.u = u << 16; return v.f;
}
__device__ __forceinline__ float bfhi(u32 u) {
    union { u32 u; float f; } v; v.u = u & 0xffff0000u; return v.f;
}
__device__ __forceinline__ u32 f2bf(float f) {   // round-to-nearest-even bf16 bits
    union { float f; u32 u; } v; v.f = f;
    return (v.u + 0x7fffu + ((v.u >> 16) & 1u)) >> 16;
}

// ---------------- edge dtype detect + convert ----------------
__global__ void detect_k(const void* ei, int* flag, int nnode) {
    const u64* p = (const u64*)ei;
    int lane = threadIdx.x & 63;
    u64 v = p[lane];
    int ok = (v < (u64)nnode);
    int all64 = __all(ok);
    if (threadIdx.x == 0) *flag = all64 ? 1 : 0;
}

__global__ void convert_edges_k(const void* ei, int* __restrict__ src, int* __restrict__ dst,
                                const int* __restrict__ flag, int E) {
    int is64 = *flag;
    int i = blockIdx.x * blockDim.x + threadIdx.x;
    int stride = gridDim.x * blockDim.x;
    if (is64) {
        const long long* p = (const long long*)ei;
        for (; i < E; i += stride) { src[i] = (int)p[i]; dst[i] = (int)p[E + i]; }
    } else {
        const int* p = (const int*)ei;
        for (; i < E; i += stride) { src[i] = p[i]; dst[i] = p[E + i]; }
    }
}

// ---------------- degree / dinv ----------------
__global__ void deg_count_k(const int* __restrict__ dst, int* __restrict__ degi, int E) {
    int i = blockIdx.x * blockDim.x + threadIdx.x;
    int stride = gridDim.x * blockDim.x;
    for (; i < E; i += stride) atomicAdd(&degi[dst[i]], 1);
}

__global__ void dinv_k(const int* __restrict__ degi, float* __restrict__ dinv, int n) {
    int i = blockIdx.x * blockDim.x + threadIdx.x;
    int stride = gridDim.x * blockDim.x;
    for (; i < n; i += stride) dinv[i] = rsqrtf((float)(degi[i] + 1)); // +1 self-loop
}

// ---------------- hierarchical exclusive scan (row_ptr) ----------------
__global__ void block_sum_k(const int* __restrict__ counts, int* __restrict__ bsum, int n) {
    __shared__ int red[4];
    int idx = blockIdx.x * 256 + threadIdx.x;
    int v = (idx < n) ? counts[idx] : 0;
#pragma unroll
    for (int m = 32; m >= 1; m >>= 1) v += __shfl_xor(v, m);
    int lane = threadIdx.x & 63, w = threadIdx.x >> 6;
    if (lane == 0) red[w] = v;
    __syncthreads();
    if (threadIdx.x == 0) bsum[blockIdx.x] = red[0] + red[1] + red[2] + red[3];
}

__global__ void scan_bsum_k(int* bsum, int nb) { // 1 block, 256 thr, nb<=256
    __shared__ int sd[256];
    int t = threadIdx.x;
    int v = (t < nb) ? bsum[t] : 0;
    sd[t] = v; __syncthreads();
    for (int off = 1; off < 256; off <<= 1) {
        int u = (t >= off) ? sd[t - off] : 0;
        __syncthreads();
        sd[t] += u;
        __syncthreads();
    }
    if (t < nb) bsum[t] = sd[t] - v; // exclusive
}

__global__ void block_scan_k(const int* __restrict__ counts, const int* __restrict__ bsum,
                             int* __restrict__ rp, int n) {
    __shared__ int sd[256];
    int t = threadIdx.x;
    int idx = blockIdx.x * 256 + t;
    int v = (idx < n) ? counts[idx] : 0;
    sd[t] = v; __syncthreads();
    for (int off = 1; off < 256; off <<= 1) {
        int u = (t >= off) ? sd[t - off] : 0;
        __syncthreads();
        sd[t] += u;
        __syncthreads();
    }
    if (idx < n) rp[idx + 1] = bsum[blockIdx.x] + sd[t];
    if (blockIdx.x == 0 && t == 0) rp[0] = 0;
}

__global__ void csr_fill_k(const int* __restrict__ src, const int* __restrict__ dst,
                           const int* __restrict__ rp, int* __restrict__ fill,
                           int* __restrict__ cs, int E) {
    int i = blockIdx.x * blockDim.x + threadIdx.x;
    int stride = gridDim.x * blockDim.x;
    for (; i < E; i += stride) {
        int d = dst[i];
        int pos = atomicAdd(&fill[d], 1);
        cs[rp[d] + pos] = src[i];
    }
}

// ---------------- conversions ----------------
__global__ void f32_to_bf16_k(const float* __restrict__ in, u16* __restrict__ out, int nquads) {
    int i = blockIdx.x * blockDim.x + threadIdx.x;
    int stride = gridDim.x * blockDim.x;
    for (; i < nquads; i += stride) {
        float4 v = ((const float4*)in)[i];
        u32 lo = f2bf(v.x) | (f2bf(v.y) << 16);
        u32 hi = f2bf(v.z) | (f2bf(v.w) << 16);
        ((uint2*)out)[i] = make_uint2(lo, hi);
    }
}

__global__ void transpose_w_k(const float* __restrict__ W, u16* __restrict__ Wt,
                              int din, int dout) {
    int i = blockIdx.x * blockDim.x + threadIdx.x;
    int total = din * dout;
    if (i < total) {
        int r = i / dout, c = i % dout;
        Wt[(size_t)c * din + r] = (u16)f2bf(W[i]);
    }
}

// ---------------- GCN aggregation: out[v] = dinv[v]*(sum_e dinv[src]*h[src]) + dinv[v]^2*h[v]
template <int DIN>
__global__ __launch_bounds__(256) void aggregate_k(
    const u16* __restrict__ H, u16* __restrict__ O,
    const float* __restrict__ dinv, const int* __restrict__ rp,
    const int* __restrict__ cs, int n)
{
    constexpr int U = DIN / 128; // u32 words per lane (1 or 2)
    int node = blockIdx.x * 4 + (threadIdx.x >> 6);
    if (node >= n) return;
    int lane = threadIdx.x & 63;
    const u32* Hu = (const u32*)H;
    float dv = dinv[node];
    float acc[2 * U];
    {
        const u32* row = Hu + (size_t)node * (DIN / 2);
#pragma unroll
        for (int j = 0; j < U; ++j) {
            u32 w = row[lane * U + j];
            acc[2 * j]     = dv * bflo(w);
            acc[2 * j + 1] = dv * bfhi(w);
        }
    }
    int e0 = rp[node], e1 = rp[node + 1];
    for (int e = e0; e < e1; ++e) {
        int s = cs[e];
        float w = dinv[s];
        const u32* row = Hu + (size_t)s * (DIN / 2);
#pragma unroll
        for (int j = 0; j < U; ++j) {
            u32 xx = row[lane * U + j];
            acc[2 * j]     = fmaf(w, bflo(xx), acc[2 * j]);
            acc[2 * j + 1] = fmaf(w, bfhi(xx), acc[2 * j + 1]);
        }
    }
    u32* orow = (u32*)O + (size_t)node * (DIN / 2);
#pragma unroll
    for (int j = 0; j < U; ++j) {
        float x0 = acc[2 * j] * dv, x1 = acc[2 * j + 1] * dv;
        orow[lane * U + j] = f2bf(x0) | (f2bf(x1) << 16);
    }
}

// ---------------- bf16 MFMA GEMM: out[M][256] = A[M][K] * Bt[256][K]^T + bias
// Fused colsum/colsumsq -> per-block partials (no global atomics).
// part layout: part[bx][ y*256 + col_local*2 + {0=s,1=q} ]
template <int K, int OUTB>
__global__ __launch_bounds__(256) void gemm_bf16(
    const u16* __restrict__ A, const u16* __restrict__ Bt,
    const float* __restrict__ bias, void* __restrict__ outp,
    float* __restrict__ part, int M)
{
    // LDS layout [k_hi=4][dim=128][k_lo=8] bf16 — conflict-free ds_read_b128,
    // linear-compatible with global_load_lds (chunk c: dim=c&127, k_hi=c>>7)
    __shared__ __align__(16) u16 lA[4096];
    __shared__ __align__(16) u16 lB[4096];
    __shared__ float red[256]; // [col_local 128][2]
    const int tid = threadIdx.x;
    const int lane = tid & 63;
    const int wid = tid >> 6;
    const int wm = wid >> 1, wn = wid & 1;
    const int l15 = lane & 15, khi = lane >> 4;
    const int row0 = blockIdx.x * 128;
    const int col0 = blockIdx.y * 128;

    f32x4 acc[4][4];
#pragma unroll
    for (int i = 0; i < 4; ++i)
#pragma unroll
        for (int j = 0; j < 4; ++j)
            acc[i][j] = (f32x4){0.f, 0.f, 0.f, 0.f};

    if (tid < 256) red[tid] = 0.f;

    for (int k0 = 0; k0 < K; k0 += 32) {
#pragma unroll
        for (int t = 0; t < 2; ++t) {
            int c = t * 256 + wid * 64 + lane;
            int r = c & 127, kh = c >> 7;
            int ar = row0 + r; if (ar > M - 1) ar = M - 1;
            const u16* ga = A + (size_t)ar * K + k0 + kh * 8;
            u16* la = &lA[(t * 256 + wid * 64) * 8];
            __builtin_amdgcn_global_load_lds(
                (const __attribute__((address_space(1))) void*)ga,
                (__attribute__((address_space(3))) void*)la, 16, 0, 0);
            const u16* gb = Bt + (size_t)(col0 + r) * K + k0 + kh * 8;
            u16* lb = &lB[(t * 256 + wid * 64) * 8];
            __builtin_amdgcn_global_load_lds(
                (const __attribute__((address_space(1))) void*)gb,
                (__attribute__((address_space(3))) void*)lb, 16, 0, 0);
        }
        __syncthreads();
        bf16x8 afr[4], bfr[4];
#pragma unroll
        for (int mi = 0; mi < 4; ++mi)
            afr[mi] = *(const bf16x8*)&lA[khi * 1024 + (wm * 64 + mi * 16 + l15) * 8];
#pragma unroll
        for (int nj = 0; nj < 4; ++nj)
            bfr[nj] = *(const bf16x8*)&lB[khi * 1024 + (wn * 64 + nj * 16 + l15) * 8];
#pragma unroll
        for (int mi = 0; mi < 4; ++mi)
#pragma unroll
            for (int nj = 0; nj < 4; ++nj)
                acc[mi][nj] = __builtin_amdgcn_mfma_f32_16x16x32_bf16(
                    afr[mi], bfr[nj], acc[mi][nj], 0, 0, 0);
        __syncthreads();
    }

#pragma unroll
    for (int mi = 0; mi < 4; ++mi) {
#pragma unroll
        for (int nj = 0; nj < 4; ++nj) {
            int coll = wn * 64 + nj * 16 + l15;
            int colg = col0 + coll;
            float bsv = bias[colg];
            float s = 0.f, q = 0.f;
#pragma unroll
            for (int i = 0; i < 4; ++i) {
                int rowg = row0 + wm * 64 + mi * 16 + khi * 4 + i;
                if (rowg < M) {
                    float v = acc[mi][nj][i] + bsv;
                    if (OUTB) ((u16*)outp)[(size_t)rowg * 256 + colg] = (u16)f2bf(v);
                    else      ((float*)outp)[(size_t)rowg * 256 + colg] = v;
                    s += v; q += v * v;
                }
            }
            s += __shfl_xor(s, 16); s += __shfl_xor(s, 32);
            q += __shfl_xor(q, 16); q += __shfl_xor(q, 32);
            if (lane < 16) {
                atomicAdd(&red[coll * 2], s);
                atomicAdd(&red[coll * 2 + 1], q);
            }
        }
    }
    __syncthreads();
    if (tid < 256)
        part[(size_t)blockIdx.x * 512 + blockIdx.y * 256 + tid] = red[tid];
}

// ---------------- BN stats: one WAVE per channel reduces partials ----------------
// grid = 64 blocks x 256 thr (4 waves); channel c = blockIdx.x*4 + wave
__global__ __launch_bounds__(256) void bn_stats_k(
    const float* __restrict__ part, const float* __restrict__ gamma,
    const float* __restrict__ beta, float* __restrict__ ss, int nbx, int M)
{
    int wave = threadIdx.x >> 6;
    int lane = threadIdx.x & 63;
    int c = blockIdx.x * 4 + wave; // 0..255
    int base = (c >> 7) * 256 + (c & 127) * 2;
    float s = 0.f, q = 0.f;
    for (int bx = lane; bx < nbx; bx += 64) {
        float2 v = *(const float2*)&part[(size_t)bx * 512 + base];
        s += v.x; q += v.y;
    }
#pragma unroll
    for (int m = 32; m >= 1; m >>= 1) {
        s += __shfl_xor(s, m);
        q += __shfl_xor(q, m);
    }
    if (lane == 0) {
        float mean = s / (float)M;
        float var = fmaxf(q / (float)M - mean * mean, 0.f);
        float sc = gamma[c] * rsqrtf(var + BN_EPS);
        ss[c] = sc;
        ss[256 + c] = beta[c] - mean * sc;
    }
}

// ---------------- BN apply + PReLU ----------------
template <int INB, int OUTB> // bf16 flags for input/output
__global__ void bn_prelu_k(const void* __restrict__ in, void* __restrict__ outp,
                           const float* __restrict__ ss,
                           const float* __restrict__ aptr, int nquads) {
    float a = aptr[0];
    int i = blockIdx.x * blockDim.x + threadIdx.x;
    int stride = gridDim.x * blockDim.x;
    for (; i < nquads; i += stride) {
        float v0, v1, v2, v3;
        if (INB) {
            uint2 u = ((const uint2*)in)[i];
            v0 = bflo(u.x); v1 = bfhi(u.x); v2 = bflo(u.y); v3 = bfhi(u.y);
        } else {
            float4 v = ((const float4*)in)[i];
            v0 = v.x; v1 = v.y; v2 = v.z; v3 = v.w;
        }
        int c0 = (i * 4) & 255;
        float r0 = v0 * ss[c0 + 0] + ss[256 + c0 + 0];
        float r1 = v1 * ss[c0 + 1] + ss[256 + c0 + 1];
        float r2 = v2 * ss[c0 + 2] + ss[256 + c0 + 2];
        float r3 = v3 * ss[c0 + 3] + ss[256 + c0 + 3];
        r0 = r0 > 0.f ? r0 : a * r0;
        r1 = r1 > 0.f ? r1 : a * r1;
        r2 = r2 > 0.f ? r2 : a * r2;
        r3 = r3 > 0.f ? r3 : a * r3;
        if (OUTB) {
            u32 lo = f2bf(r0) | (f2bf(r1) << 16);
            u32 hi = f2bf(r2) | (f2bf(r3) << 16);
            ((uint2*)outp)[i] = make_uint2(lo, hi);
        } else {
            ((float4*)outp)[i] = make_float4(r0, r1, r2, r3);
        }
    }
}

extern "C" void kernel_launch(void* const* d_in, const int* in_sizes, int n_in,
                              void* d_out, int out_size, void* d_ws, size_t ws_size,
                              hipStream_t stream) {
    const float* x   = (const float*)d_in[0];
    const void*  ei  = d_in[1];
    const float* W0  = (const float*)d_in[2];
    const float* b0  = (const float*)d_in[3];
    const float* g0  = (const float*)d_in[4];
    const float* be0 = (const float*)d_in[5];
    const float* a0  = (const float*)d_in[6];
    const float* W1  = (const float*)d_in[7];
    const float* b1  = (const float*)d_in[8];
    const float* g1  = (const float*)d_in[9];
    const float* be1 = (const float*)d_in[10];
    const float* a1  = (const float*)d_in[11];
    float* out = (float*)d_out;

    const int n = in_sizes[0] / 128;
    const int E = in_sizes[1] / 2;
    const int nbx = (n + 127) / 128;

    char* ws = (char*)d_ws;
    size_t off = 0;
    auto alloc = [&](size_t bytes) {
        size_t r = off; off += (bytes + 255) & ~(size_t)255; return r;
    };
    size_t o_src  = alloc((size_t)E * 4);
    size_t o_dst  = alloc((size_t)E * 4);
    size_t o_deg  = alloc((size_t)n * 4);
    size_t o_fill = alloc((size_t)n * 4);
    size_t o_rp   = alloc((size_t)(n + 1) * 4);
    size_t o_bsum = alloc(4096);
    size_t o_flag = alloc(256);
    size_t o_dinv = alloc((size_t)n * 4);
    size_t o_csr  = alloc((size_t)E * 4);
    size_t o_part = alloc((size_t)nbx * 512 * 4);
    size_t o_ss   = alloc(2048);
    size_t o_wt0  = alloc(256 * 128 * 2);
    size_t o_wt1  = alloc(256 * 256 * 2);
    size_t o_xh   = alloc((size_t)n * 128 * 2);
    size_t o_agg0 = alloc((size_t)n * 128 * 2);
    size_t o_y0   = alloc((size_t)n * 256 * 2);
    size_t o_agg1 = o_xh; // overlay: xh+agg0 are dead by the time agg1 is written

    int*   src32 = (int*)(ws + o_src);
    int*   dst32 = (int*)(ws + o_dst);
    int*   degi  = (int*)(ws + o_deg);
    int*   fill  = (int*)(ws + o_fill);
    int*   rp    = (int*)(ws + o_rp);
    int*   bsum  = (int*)(ws + o_bsum);
    int*   flag  = (int*)(ws + o_flag);
    float* dinv  = (float*)(ws + o_dinv);
    int*   csr   = (int*)(ws + o_csr);
    float* part  = (float*)(ws + o_part);
    float* ssbuf = (float*)(ws + o_ss);
    u16*   wt0   = (u16*)(ws + o_wt0);
    u16*   wt1   = (u16*)(ws + o_wt1);
    u16*   xh    = (u16*)(ws + o_xh);
    u16*   agg0  = (u16*)(ws + o_agg0);
    u16*   y0    = (u16*)(ws + o_y0);
    u16*   agg1  = (u16*)(ws + o_agg1);

    hipMemsetAsync(ws + o_deg, 0, (size_t)n * 4, stream);
    hipMemsetAsync(ws + o_fill, 0, (size_t)n * 4, stream);

    const int gE = (E + 255) / 256 < 4096 ? (E + 255) / 256 : 4096;
    const int gN = (n + 255) / 256; // 196 for n=50000 (fits single-block scan of bsum)

    detect_k<<<1, 64, 0, stream>>>(ei, flag, n);
    convert_edges_k<<<gE, 256, 0, stream>>>(ei, src32, dst32, flag, E);
    deg_count_k<<<gE, 256, 0, stream>>>(dst32, degi, E);
    dinv_k<<<gN, 256, 0, stream>>>(degi, dinv, n);
    block_sum_k<<<gN, 256, 0, stream>>>(degi, bsum, n);
    scan_bsum_k<<<1, 256, 0, stream>>>(bsum, gN);
    block_scan_k<<<gN, 256, 0, stream>>>(degi, bsum, rp, n);
    csr_fill_k<<<gE, 256, 0, stream>>>(src32, dst32, rp, fill, csr, E);

    f32_to_bf16_k<<<4096, 256, 0, stream>>>(x, xh, n * 128 / 4);
    transpose_w_k<<<(128 * 256 + 255) / 256, 256, 0, stream>>>(W0, wt0, 128, 256);
    transpose_w_k<<<(256 * 256 + 255) / 256, 256, 0, stream>>>(W1, wt1, 256, 256);

    const dim3 ggrid(nbx, 2);

    // ---- layer 0 ----  (pre-BN output as bf16 into d_out scratch)
    aggregate_k<128><<<(n + 3) / 4, 256, 0, stream>>>(xh, agg0, dinv, rp, csr, n);
    gemm_bf16<128, 1><<<ggrid, 256, 0, stream>>>(agg0, wt0, b0, d_out, part, n);
    bn_stats_k<<<64, 256, 0, stream>>>(part, g0, be0, ssbuf, nbx, n);
    bn_prelu_k<1, 1><<<4096, 256, 0, stream>>>(d_out, y0, ssbuf, a0, n * 256 / 4);

    // ---- layer 1 ----  (f32 into d_out, BN+PReLU in place)
    aggregate_k<256><<<(n + 3) / 4, 256, 0, stream>>>(y0, agg1, dinv, rp, csr, n);
    gemm_bf16<256, 0><<<ggrid, 256, 0, stream>>>(agg1, wt1, b1, d_out, part, n);
    bn_stats_k<<<64, 256, 0, stream>>>(part, g1, be1, ssbuf, nbx, n);
    bn_prelu_k<0, 0><<<4096, 256, 0, stream>>>(out, out, ssbuf, a1, n * 256 / 4);
}

// Round 4
// 319.221 us; speedup vs baseline: 1.8423x; 1.2273x over previous
//
#include <hip/hip_runtime.h>

typedef unsigned int u32;
typedef unsigned short u16;
typedef unsigned long long u64;

using f32x4 = __attribute__((ext_vector_type(4))) float;
using bf16x8 = __attribute__((ext_vector_type(8))) short;

#define BN_EPS 1e-5f

__device__ __forceinline__ float bflo(u32 u) {
    union { u32 u; float f; } v; v.u = u << 16; return v.f;
}
__device__ __forceinline__ float bfhi(u32 u) {
    union { u32 u; float f; } v; v.u = u & 0xffff0000u; return v.f;
}
__device__ __forceinline__ u32 f2bf(float f) {   // round-to-nearest-even bf16 bits
    union { float f; u32 u; } v; v.f = f;
    return (v.u + 0x7fffu + ((v.u >> 16) & 1u)) >> 16;
}

// ---------------- edge dtype detect ----------------
__global__ void detect_k(const void* ei, int* flag, int nnode) {
    const u64* p = (const u64*)ei;
    int lane = threadIdx.x & 63;
    u64 v = p[lane];
    int ok = (v < (u64)nnode);
    int all64 = __all(ok);
    if (threadIdx.x == 0) *flag = all64 ? 1 : 0;
}

// ---------------- degree (direct from edge_index) ----------------
__global__ void deg_count_k(const void* ei, const int* __restrict__ flag,
                            int* __restrict__ degi, int E) {
    int is64 = *flag;
    int i = blockIdx.x * blockDim.x + threadIdx.x;
    int stride = gridDim.x * blockDim.x;
    if (is64) {
        const long long* p = (const long long*)ei;
        for (; i < E; i += stride) atomicAdd(&degi[(int)p[(size_t)E + i]], 1);
    } else {
        const int* p = (const int*)ei;
        for (; i < E; i += stride) atomicAdd(&degi[p[(size_t)E + i]], 1);
    }
}

__global__ void dinv_k(const int* __restrict__ degi, float* __restrict__ dinv, int n) {
    int i = blockIdx.x * blockDim.x + threadIdx.x;
    int stride = gridDim.x * blockDim.x;
    for (; i < n; i += stride) dinv[i] = rsqrtf((float)(degi[i] + 1)); // +1 self-loop
}

// ---------------- hierarchical exclusive scan (row_ptr) ----------------
__global__ void block_sum_k(const int* __restrict__ counts, int* __restrict__ bsum, int n) {
    __shared__ int red[4];
    int idx = blockIdx.x * 256 + threadIdx.x;
    int v = (idx < n) ? counts[idx] : 0;
#pragma unroll
    for (int m = 32; m >= 1; m >>= 1) v += __shfl_xor(v, m);
    int lane = threadIdx.x & 63, w = threadIdx.x >> 6;
    if (lane == 0) red[w] = v;
    __syncthreads();
    if (threadIdx.x == 0) bsum[blockIdx.x] = red[0] + red[1] + red[2] + red[3];
}

__global__ void scan_bsum_k(int* bsum, int nb) { // 1 block, 256 thr, nb<=256
    __shared__ int sd[256];
    int t = threadIdx.x;
    int v = (t < nb) ? bsum[t] : 0;
    sd[t] = v; __syncthreads();
    for (int off = 1; off < 256; off <<= 1) {
        int u = (t >= off) ? sd[t - off] : 0;
        __syncthreads();
        sd[t] += u;
        __syncthreads();
    }
    if (t < nb) bsum[t] = sd[t] - v; // exclusive
}

__global__ void block_scan_k(const int* __restrict__ counts, const int* __restrict__ bsum,
                             int* __restrict__ rp, int n) {
    __shared__ int sd[256];
    int t = threadIdx.x;
    int idx = blockIdx.x * 256 + t;
    int v = (idx < n) ? counts[idx] : 0;
    sd[t] = v; __syncthreads();
    for (int off = 1; off < 256; off <<= 1) {
        int u = (t >= off) ? sd[t - off] : 0;
        __syncthreads();
        sd[t] += u;
        __syncthreads();
    }
    if (idx < n) rp[idx + 1] = bsum[blockIdx.x] + sd[t];
    if (blockIdx.x == 0 && t == 0) rp[0] = 0;
}

// ---------------- CSR fill: entry = {src, dinv[src] bits} ----------------
__global__ void csr_fill_k(const void* ei, const int* __restrict__ flag,
                           const float* __restrict__ dinv, const int* __restrict__ rp,
                           int* __restrict__ fill, uint2* __restrict__ csrv, int E) {
    int is64 = *flag;
    int i = blockIdx.x * blockDim.x + threadIdx.x;
    int stride = gridDim.x * blockDim.x;
    for (; i < E; i += stride) {
        int s, d;
        if (is64) {
            const long long* p = (const long long*)ei;
            s = (int)p[i]; d = (int)p[(size_t)E + i];
        } else {
            const int* p = (const int*)ei;
            s = p[i]; d = p[(size_t)E + i];
        }
        int pos = atomicAdd(&fill[d], 1);
        csrv[rp[d] + pos] = make_uint2((u32)s, __float_as_uint(dinv[s]));
    }
}

// ---------------- conversions ----------------
__global__ void f32_to_bf16_k(const float* __restrict__ in, u16* __restrict__ out, int nquads) {
    int i = blockIdx.x * blockDim.x + threadIdx.x;
    int stride = gridDim.x * blockDim.x;
    for (; i < nquads; i += stride) {
        float4 v = ((const float4*)in)[i];
        u32 lo = f2bf(v.x) | (f2bf(v.y) << 16);
        u32 hi = f2bf(v.z) | (f2bf(v.w) << 16);
        ((uint2*)out)[i] = make_uint2(lo, hi);
    }
}

__global__ void transpose_w_k(const float* __restrict__ W, u16* __restrict__ Wt,
                              int din, int dout) {
    int i = blockIdx.x * blockDim.x + threadIdx.x;
    int total = din * dout;
    if (i < total) {
        int r = i / dout, c = i % dout;
        Wt[(size_t)c * din + r] = (u16)f2bf(W[i]);
    }
}

// ---------------- GCN aggregation ----------------
// out[v] = dinv[v]*( sum_e dinv[src]*h[src] + dinv[v]*h[v] )
// One wave per node. Lane-groups of RL=DIN/8 lanes each read one full row
// (16 B = 8 bf16 per lane); EPW=64/RL edges processed concurrently.
template <int DIN>
__global__ __launch_bounds__(256) void aggregate_k(
    const u16* __restrict__ H, u16* __restrict__ O,
    const float* __restrict__ dinv, const int* __restrict__ rp,
    const uint2* __restrict__ csrv, int n)
{
    constexpr int RL = DIN / 8;      // lanes per row (16 or 32)
    constexpr int EPW = 64 / RL;     // edge streams per wave (4 or 2)
    int node = blockIdx.x * 4 + (threadIdx.x >> 6);
    if (node >= n) return;
    int lane = threadIdx.x & 63;
    int li = lane & (RL - 1);        // lane within row-group
    int g = lane / RL;               // group id

    float acc[8];
    float dv = dinv[node];
    if (g == 0) {
        uint4 r = *(const uint4*)(H + (size_t)node * DIN + li * 8);
        acc[0] = dv * bflo(r.x); acc[1] = dv * bfhi(r.x);
        acc[2] = dv * bflo(r.y); acc[3] = dv * bfhi(r.y);
        acc[4] = dv * bflo(r.z); acc[5] = dv * bfhi(r.z);
        acc[6] = dv * bflo(r.w); acc[7] = dv * bfhi(r.w);
    } else {
#pragma unroll
        for (int j = 0; j < 8; ++j) acc[j] = 0.f;
    }

    int e0 = rp[node], e1 = rp[node + 1];
    for (int e = e0 + g; e < e1; e += EPW) {
        uint2 cv = csrv[e];
        uint4 r = *(const uint4*)(H + (size_t)cv.x * DIN + li * 8);
        float w = __uint_as_float(cv.y);
        acc[0] = fmaf(w, bflo(r.x), acc[0]);
        acc[1] = fmaf(w, bfhi(r.x), acc[1]);
        acc[2] = fmaf(w, bflo(r.y), acc[2]);
        acc[3] = fmaf(w, bfhi(r.y), acc[3]);
        acc[4] = fmaf(w, bflo(r.z), acc[4]);
        acc[5] = fmaf(w, bfhi(r.z), acc[5]);
        acc[6] = fmaf(w, bflo(r.w), acc[6]);
        acc[7] = fmaf(w, bfhi(r.w), acc[7]);
    }

    // combine partial sums across edge-groups
#pragma unroll
    for (int j = 0; j < 8; ++j) {
        if (EPW == 4) acc[j] += __shfl_xor(acc[j], 16);
        acc[j] += __shfl_xor(acc[j], 32);
    }

    if (g == 0) {
        uint4 o;
        o.x = f2bf(acc[0] * dv) | (f2bf(acc[1] * dv) << 16);
        o.y = f2bf(acc[2] * dv) | (f2bf(acc[3] * dv) << 16);
        o.z = f2bf(acc[4] * dv) | (f2bf(acc[5] * dv) << 16);
        o.w = f2bf(acc[6] * dv) | (f2bf(acc[7] * dv) << 16);
        *(uint4*)(O + (size_t)node * DIN + li * 8) = o;
    }
}

// ---------------- bf16 MFMA GEMM: out[M][256] = A[M][K] * Bt[256][K]^T + bias
// Fused colsum/colsumsq -> per-block partials (no global atomics).
template <int K, int OUTB>
__global__ __launch_bounds__(256) void gemm_bf16(
    const u16* __restrict__ A, const u16* __restrict__ Bt,
    const float* __restrict__ bias, void* __restrict__ outp,
    float* __restrict__ part, int M)
{
    __shared__ __align__(16) u16 lA[4096];
    __shared__ __align__(16) u16 lB[4096];
    __shared__ float red[256];
    const int tid = threadIdx.x;
    const int lane = tid & 63;
    const int wid = tid >> 6;
    const int wm = wid >> 1, wn = wid & 1;
    const int l15 = lane & 15, khi = lane >> 4;
    const int row0 = blockIdx.x * 128;
    const int col0 = blockIdx.y * 128;

    f32x4 acc[4][4];
#pragma unroll
    for (int i = 0; i < 4; ++i)
#pragma unroll
        for (int j = 0; j < 4; ++j)
            acc[i][j] = (f32x4){0.f, 0.f, 0.f, 0.f};

    if (tid < 256) red[tid] = 0.f;

    for (int k0 = 0; k0 < K; k0 += 32) {
#pragma unroll
        for (int t = 0; t < 2; ++t) {
            int c = t * 256 + wid * 64 + lane;
            int r = c & 127, kh = c >> 7;
            int ar = row0 + r; if (ar > M - 1) ar = M - 1;
            const u16* ga = A + (size_t)ar * K + k0 + kh * 8;
            u16* la = &lA[(t * 256 + wid * 64) * 8];
            __builtin_amdgcn_global_load_lds(
                (const __attribute__((address_space(1))) void*)ga,
                (__attribute__((address_space(3))) void*)la, 16, 0, 0);
            const u16* gb = Bt + (size_t)(col0 + r) * K + k0 + kh * 8;
            u16* lb = &lB[(t * 256 + wid * 64) * 8];
            __builtin_amdgcn_global_load_lds(
                (const __attribute__((address_space(1))) void*)gb,
                (__attribute__((address_space(3))) void*)lb, 16, 0, 0);
        }
        __syncthreads();
        bf16x8 afr[4], bfr[4];
#pragma unroll
        for (int mi = 0; mi < 4; ++mi)
            afr[mi] = *(const bf16x8*)&lA[khi * 1024 + (wm * 64 + mi * 16 + l15) * 8];
#pragma unroll
        for (int nj = 0; nj < 4; ++nj)
            bfr[nj] = *(const bf16x8*)&lB[khi * 1024 + (wn * 64 + nj * 16 + l15) * 8];
#pragma unroll
        for (int mi = 0; mi < 4; ++mi)
#pragma unroll
            for (int nj = 0; nj < 4; ++nj)
                acc[mi][nj] = __builtin_amdgcn_mfma_f32_16x16x32_bf16(
                    afr[mi], bfr[nj], acc[mi][nj], 0, 0, 0);
        __syncthreads();
    }

#pragma unroll
    for (int mi = 0; mi < 4; ++mi) {
#pragma unroll
        for (int nj = 0; nj < 4; ++nj) {
            int coll = wn * 64 + nj * 16 + l15;
            int colg = col0 + coll;
            float bsv = bias[colg];
            float s = 0.f, q = 0.f;
#pragma unroll
            for (int i = 0; i < 4; ++i) {
                int rowg = row0 + wm * 64 + mi * 16 + khi * 4 + i;
                if (rowg < M) {
                    float v = acc[mi][nj][i] + bsv;
                    if (OUTB) ((u16*)outp)[(size_t)rowg * 256 + colg] = (u16)f2bf(v);
                    else      ((float*)outp)[(size_t)rowg * 256 + colg] = v;
                    s += v; q += v * v;
                }
            }
            s += __shfl_xor(s, 16); s += __shfl_xor(s, 32);
            q += __shfl_xor(q, 16); q += __shfl_xor(q, 32);
            if (lane < 16) {
                atomicAdd(&red[coll * 2], s);
                atomicAdd(&red[coll * 2 + 1], q);
            }
        }
    }
    __syncthreads();
    if (tid < 256)
        part[(size_t)blockIdx.x * 512 + blockIdx.y * 256 + tid] = red[tid];
}

// ---------------- BN stats: one WAVE per channel reduces partials ----------------
__global__ __launch_bounds__(256) void bn_stats_k(
    const float* __restrict__ part, const float* __restrict__ gamma,
    const float* __restrict__ beta, float* __restrict__ ss, int nbx, int M)
{
    int wave = threadIdx.x >> 6;
    int lane = threadIdx.x & 63;
    int c = blockIdx.x * 4 + wave; // 0..255
    int base = (c >> 7) * 256 + (c & 127) * 2;
    float s = 0.f, q = 0.f;
    for (int bx = lane; bx < nbx; bx += 64) {
        float2 v = *(const float2*)&part[(size_t)bx * 512 + base];
        s += v.x; q += v.y;
    }
#pragma unroll
    for (int m = 32; m >= 1; m >>= 1) {
        s += __shfl_xor(s, m);
        q += __shfl_xor(q, m);
    }
    if (lane == 0) {
        float mean = s / (float)M;
        float var = fmaxf(q / (float)M - mean * mean, 0.f);
        float sc = gamma[c] * rsqrtf(var + BN_EPS);
        ss[c] = sc;
        ss[256 + c] = beta[c] - mean * sc;
    }
}

// ---------------- BN apply + PReLU ----------------
template <int INB, int OUTB> // bf16 flags for input/output
__global__ void bn_prelu_k(const void* __restrict__ in, void* __restrict__ outp,
                           const float* __restrict__ ss,
                           const float* __restrict__ aptr, int nquads) {
    float a = aptr[0];
    int i = blockIdx.x * blockDim.x + threadIdx.x;
    int stride = gridDim.x * blockDim.x;
    for (; i < nquads; i += stride) {
        float v0, v1, v2, v3;
        if (INB) {
            uint2 u = ((const uint2*)in)[i];
            v0 = bflo(u.x); v1 = bfhi(u.x); v2 = bflo(u.y); v3 = bfhi(u.y);
        } else {
            float4 v = ((const float4*)in)[i];
            v0 = v.x; v1 = v.y; v2 = v.z; v3 = v.w;
        }
        int c0 = (i * 4) & 255;
        float r0 = v0 * ss[c0 + 0] + ss[256 + c0 + 0];
        float r1 = v1 * ss[c0 + 1] + ss[256 + c0 + 1];
        float r2 = v2 * ss[c0 + 2] + ss[256 + c0 + 2];
        float r3 = v3 * ss[c0 + 3] + ss[256 + c0 + 3];
        r0 = r0 > 0.f ? r0 : a * r0;
        r1 = r1 > 0.f ? r1 : a * r1;
        r2 = r2 > 0.f ? r2 : a * r2;
        r3 = r3 > 0.f ? r3 : a * r3;
        if (OUTB) {
            u32 lo = f2bf(r0) | (f2bf(r1) << 16);
            u32 hi = f2bf(r2) | (f2bf(r3) << 16);
            ((uint2*)outp)[i] = make_uint2(lo, hi);
        } else {
            ((float4*)outp)[i] = make_float4(r0, r1, r2, r3);
        }
    }
}

extern "C" void kernel_launch(void* const* d_in, const int* in_sizes, int n_in,
                              void* d_out, int out_size, void* d_ws, size_t ws_size,
                              hipStream_t stream) {
    const float* x   = (const float*)d_in[0];
    const void*  ei  = d_in[1];
    const float* W0  = (const float*)d_in[2];
    const float* b0  = (const float*)d_in[3];
    const float* g0  = (const float*)d_in[4];
    const float* be0 = (const float*)d_in[5];
    const float* a0  = (const float*)d_in[6];
    const float* W1  = (const float*)d_in[7];
    const float* b1  = (const float*)d_in[8];
    const float* g1  = (const float*)d_in[9];
    const float* be1 = (const float*)d_in[10];
    const float* a1  = (const float*)d_in[11];
    float* out = (float*)d_out;

    const int n = in_sizes[0] / 128;
    const int E = in_sizes[1] / 2;
    const int nbx = (n + 127) / 128;

    char* ws = (char*)d_ws;
    size_t off = 0;
    auto alloc = [&](size_t bytes) {
        size_t r = off; off += (bytes + 255) & ~(size_t)255; return r;
    };
    size_t o_deg  = alloc((size_t)n * 4);
    size_t o_fill = alloc((size_t)n * 4);
    size_t o_rp   = alloc((size_t)(n + 1) * 4);
    size_t o_bsum = alloc(4096);
    size_t o_flag = alloc(256);
    size_t o_dinv = alloc((size_t)n * 4);
    size_t o_csr  = alloc((size_t)E * 8);       // uint2 {src, dinv[src]}
    size_t o_part = alloc((size_t)nbx * 512 * 4);
    size_t o_ss   = alloc(2048);
    size_t o_wt0  = alloc(256 * 128 * 2);
    size_t o_wt1  = alloc(256 * 256 * 2);
    size_t o_xh   = alloc((size_t)n * 128 * 2);
    size_t o_agg0 = alloc((size_t)n * 128 * 2);
    size_t o_y0   = alloc((size_t)n * 256 * 2);
    size_t o_agg1 = o_xh; // overlay: xh+agg0 dead by the time agg1 is written

    int*   degi  = (int*)(ws + o_deg);
    int*   fill  = (int*)(ws + o_fill);
    int*   rp    = (int*)(ws + o_rp);
    int*   bsum  = (int*)(ws + o_bsum);
    int*   flag  = (int*)(ws + o_flag);
    float* dinv  = (float*)(ws + o_dinv);
    uint2* csrv  = (uint2*)(ws + o_csr);
    float* part  = (float*)(ws + o_part);
    float* ssbuf = (float*)(ws + o_ss);
    u16*   wt0   = (u16*)(ws + o_wt0);
    u16*   wt1   = (u16*)(ws + o_wt1);
    u16*   xh    = (u16*)(ws + o_xh);
    u16*   agg0  = (u16*)(ws + o_agg0);
    u16*   y0    = (u16*)(ws + o_y0);
    u16*   agg1  = (u16*)(ws + o_agg1);

    hipMemsetAsync(ws + o_deg, 0, (size_t)n * 4, stream);
    hipMemsetAsync(ws + o_fill, 0, (size_t)n * 4, stream);

    const int gE = (E + 255) / 256 < 4096 ? (E + 255) / 256 : 4096;
    const int gN = (n + 255) / 256;

    detect_k<<<1, 64, 0, stream>>>(ei, flag, n);
    deg_count_k<<<gE, 256, 0, stream>>>(ei, flag, degi, E);
    dinv_k<<<gN, 256, 0, stream>>>(degi, dinv, n);
    block_sum_k<<<gN, 256, 0, stream>>>(degi, bsum, n);
    scan_bsum_k<<<1, 256, 0, stream>>>(bsum, gN);
    block_scan_k<<<gN, 256, 0, stream>>>(degi, bsum, rp, n);
    csr_fill_k<<<gE, 256, 0, stream>>>(ei, flag, dinv, rp, fill, csrv, E);

    f32_to_bf16_k<<<4096, 256, 0, stream>>>(x, xh, n * 128 / 4);
    transpose_w_k<<<(128 * 256 + 255) / 256, 256, 0, stream>>>(W0, wt0, 128, 256);
    transpose_w_k<<<(256 * 256 + 255) / 256, 256, 0, stream>>>(W1, wt1, 256, 256);

    const dim3 ggrid(nbx, 2);

    // ---- layer 0 ----  (pre-BN bf16 into d_out scratch)
    aggregate_k<128><<<(n + 3) / 4, 256, 0, stream>>>(xh, agg0, dinv, rp, csrv, n);
    gemm_bf16<128, 1><<<ggrid, 256, 0, stream>>>(agg0, wt0, b0, d_out, part, n);
    bn_stats_k<<<64, 256, 0, stream>>>(part, g0, be0, ssbuf, nbx, n);
    bn_prelu_k<1, 1><<<4096, 256, 0, stream>>>(d_out, y0, ssbuf, a0, n * 256 / 4);

    // ---- layer 1 ----  (pre-BN bf16 into y0 — dead after aggregate; final f32 to d_out)
    aggregate_k<256><<<(n + 3) / 4, 256, 0, stream>>>(y0, agg1, dinv, rp, csrv, n);
    gemm_bf16<256, 1><<<ggrid, 256, 0, stream>>>(agg1, wt1, b1, y0, part, n);
    bn_stats_k<<<64, 256, 0, stream>>>(part, g1, be1, ssbuf, nbx, n);
    bn_prelu_k<1, 0><<<4096, 256, 0, stream>>>(y0, out, ssbuf, a1, n * 256 / 4);
}

// Round 6
// 308.233 us; speedup vs baseline: 1.9080x; 1.0356x over previous
//
#include <hip/hip_runtime.h>

typedef unsigned int u32;
typedef unsigned short u16;
typedef unsigned long long u64;

using f32x4 = __attribute__((ext_vector_type(4))) float;
using bf16x8 = __attribute__((ext_vector_type(8))) short;

#define BN_EPS 1e-5f

__device__ __forceinline__ float bflo(u32 u) {
    union { u32 u; float f; } v; v.u = u << 16; return v.f;
}
__device__ __forceinline__ float bfhi(u32 u) {
    union { u32 u; float f; } v; v.u = u & 0xffff0000u; return v.f;
}
__device__ __forceinline__ u32 f2bf(float f) {   // round-to-nearest-even bf16 bits
    union { float f; u32 u; } v; v.f = f;
    return (v.u + 0x7fffu + ((v.u >> 16) & 1u)) >> 16;
}

// ---------------- edge dtype detect ----------------
__global__ void detect_k(const void* ei, int* flag, int nnode) {
    const u64* p = (const u64*)ei;
    int lane = threadIdx.x & 63;
    u64 v = p[lane];
    int ok = (v < (u64)nnode);
    int all64 = __all(ok);
    if (threadIdx.x == 0) *flag = all64 ? 1 : 0;
}

// ---------------- degree (direct from edge_index) ----------------
__global__ void deg_count_k(const void* ei, const int* __restrict__ flag,
                            int* __restrict__ degi, int E) {
    int is64 = *flag;
    int i = blockIdx.x * blockDim.x + threadIdx.x;
    int stride = gridDim.x * blockDim.x;
    if (is64) {
        const long long* p = (const long long*)ei;
        for (; i < E; i += stride) atomicAdd(&degi[(int)p[(size_t)E + i]], 1);
    } else {
        const int* p = (const int*)ei;
        for (; i < E; i += stride) atomicAdd(&degi[p[(size_t)E + i]], 1);
    }
}

__global__ void dinv_k(const int* __restrict__ degi, float* __restrict__ dinv, int n) {
    int i = blockIdx.x * blockDim.x + threadIdx.x;
    int stride = gridDim.x * blockDim.x;
    for (; i < n; i += stride) dinv[i] = rsqrtf((float)(degi[i] + 1)); // +1 self-loop
}

// ---------------- hierarchical exclusive scan (row_ptr) ----------------
__global__ void block_sum_k(const int* __restrict__ counts, int* __restrict__ bsum, int n) {
    __shared__ int red[4];
    int idx = blockIdx.x * 256 + threadIdx.x;
    int v = (idx < n) ? counts[idx] : 0;
#pragma unroll
    for (int m = 32; m >= 1; m >>= 1) v += __shfl_xor(v, m);
    int lane = threadIdx.x & 63, w = threadIdx.x >> 6;
    if (lane == 0) red[w] = v;
    __syncthreads();
    if (threadIdx.x == 0) bsum[blockIdx.x] = red[0] + red[1] + red[2] + red[3];
}

__global__ void scan_bsum_k(int* bsum, int nb) { // 1 block, 256 thr, nb<=256
    __shared__ int sd[256];
    int t = threadIdx.x;
    int v = (t < nb) ? bsum[t] : 0;
    sd[t] = v; __syncthreads();
    for (int off = 1; off < 256; off <<= 1) {
        int u = (t >= off) ? sd[t - off] : 0;
        __syncthreads();
        sd[t] += u;
        __syncthreads();
    }
    if (t < nb) bsum[t] = sd[t] - v; // exclusive
}

__global__ void block_scan_k(const int* __restrict__ counts, const int* __restrict__ bsum,
                             int* __restrict__ rp, int n) {
    __shared__ int sd[256];
    int t = threadIdx.x;
    int idx = blockIdx.x * 256 + t;
    int v = (idx < n) ? counts[idx] : 0;
    sd[t] = v; __syncthreads();
    for (int off = 1; off < 256; off <<= 1) {
        int u = (t >= off) ? sd[t - off] : 0;
        __syncthreads();
        sd[t] += u;
        __syncthreads();
    }
    if (idx < n) rp[idx + 1] = bsum[blockIdx.x] + sd[t];
    if (blockIdx.x == 0 && t == 0) rp[0] = 0;
}

// ---------------- CSR fill: entry = {src, dinv[src] bits} ----------------
__global__ void csr_fill_k(const void* ei, const int* __restrict__ flag,
                           const float* __restrict__ dinv, const int* __restrict__ rp,
                           int* __restrict__ fill, uint2* __restrict__ csrv, int E) {
    int is64 = *flag;
    int i = blockIdx.x * blockDim.x + threadIdx.x;
    int stride = gridDim.x * blockDim.x;
    for (; i < E; i += stride) {
        int s, d;
        if (is64) {
            const long long* p = (const long long*)ei;
            s = (int)p[i]; d = (int)p[(size_t)E + i];
        } else {
            const int* p = (const int*)ei;
            s = p[i]; d = p[(size_t)E + i];
        }
        int pos = atomicAdd(&fill[d], 1);
        csrv[rp[d] + pos] = make_uint2((u32)s, __float_as_uint(dinv[s]));
    }
}

// ---------------- conversions ----------------
__global__ void f32_to_bf16_k(const float* __restrict__ in, u16* __restrict__ out, int nquads) {
    int i = blockIdx.x * blockDim.x + threadIdx.x;
    int stride = gridDim.x * blockDim.x;
    for (; i < nquads; i += stride) {
        float4 v = ((const float4*)in)[i];
        u32 lo = f2bf(v.x) | (f2bf(v.y) << 16);
        u32 hi = f2bf(v.z) | (f2bf(v.w) << 16);
        ((uint2*)out)[i] = make_uint2(lo, hi);
    }
}

__global__ void transpose_w_k(const float* __restrict__ W, u16* __restrict__ Wt,
                              int din, int dout) {
    int i = blockIdx.x * blockDim.x + threadIdx.x;
    int total = din * dout;
    if (i < total) {
        int r = i / dout, c = i % dout;
        Wt[(size_t)c * din + r] = (u16)f2bf(W[i]);
    }
}

// ---------------- GCN aggregation ----------------
// out[v] = dinv[v]*( sum_e dinv[src]*h[src] + dinv[v]*h[v] )
// One wave per node; lane-groups of RL=DIN/8 lanes read one row (16 B/lane).
// Edge loop manually unrolled 4x: 4 independent CSR-entry loads then 4
// independent row-gathers in flight per lane-group (8/16 per wave).
__device__ __forceinline__ void fma8(float wgt, uint4 r, float* acc) {
    acc[0] = fmaf(wgt, bflo(r.x), acc[0]);
    acc[1] = fmaf(wgt, bfhi(r.x), acc[1]);
    acc[2] = fmaf(wgt, bflo(r.y), acc[2]);
    acc[3] = fmaf(wgt, bfhi(r.y), acc[3]);
    acc[4] = fmaf(wgt, bflo(r.z), acc[4]);
    acc[5] = fmaf(wgt, bfhi(r.z), acc[5]);
    acc[6] = fmaf(wgt, bflo(r.w), acc[6]);
    acc[7] = fmaf(wgt, bfhi(r.w), acc[7]);
}

template <int DIN>
__global__ __launch_bounds__(256) void aggregate_k(
    const u16* __restrict__ H, u16* __restrict__ O,
    const float* __restrict__ dinv, const int* __restrict__ rp,
    const uint2* __restrict__ csrv, int n)
{
    constexpr int RL = DIN / 8;      // lanes per row (16 or 32)
    constexpr int EPW = 64 / RL;     // edge streams per wave (4 or 2)
    int node = blockIdx.x * 4 + (threadIdx.x >> 6);
    if (node >= n) return;
    int lane = threadIdx.x & 63;
    int li = lane & (RL - 1);        // lane within row-group
    int g = lane / RL;               // group id

    float acc[8];
    float dv = dinv[node];
    if (g == 0) {
        uint4 r = *(const uint4*)(H + (size_t)node * DIN + li * 8);
        acc[0] = dv * bflo(r.x); acc[1] = dv * bfhi(r.x);
        acc[2] = dv * bflo(r.y); acc[3] = dv * bfhi(r.y);
        acc[4] = dv * bflo(r.z); acc[5] = dv * bfhi(r.z);
        acc[6] = dv * bflo(r.w); acc[7] = dv * bfhi(r.w);
    } else {
#pragma unroll
        for (int j = 0; j < 8; ++j) acc[j] = 0.f;
    }

    int e0 = rp[node], e1 = rp[node + 1];
    int e = e0 + g;
    // 4x unrolled: 4 independent gather chains in flight per group
    for (; e + 3 * EPW < e1; e += 4 * EPW) {
        uint2 cv0 = csrv[e];
        uint2 cv1 = csrv[e + EPW];
        uint2 cv2 = csrv[e + 2 * EPW];
        uint2 cv3 = csrv[e + 3 * EPW];
        uint4 r0 = *(const uint4*)(H + (size_t)cv0.x * DIN + li * 8);
        uint4 r1 = *(const uint4*)(H + (size_t)cv1.x * DIN + li * 8);
        uint4 r2 = *(const uint4*)(H + (size_t)cv2.x * DIN + li * 8);
        uint4 r3 = *(const uint4*)(H + (size_t)cv3.x * DIN + li * 8);
        fma8(__uint_as_float(cv0.y), r0, acc);
        fma8(__uint_as_float(cv1.y), r1, acc);
        fma8(__uint_as_float(cv2.y), r2, acc);
        fma8(__uint_as_float(cv3.y), r3, acc);
    }
    for (; e < e1; e += EPW) {
        uint2 cv = csrv[e];
        uint4 r = *(const uint4*)(H + (size_t)cv.x * DIN + li * 8);
        fma8(__uint_as_float(cv.y), r, acc);
    }

    // combine partial sums across edge-groups
#pragma unroll
    for (int j = 0; j < 8; ++j) {
        if (EPW == 4) acc[j] += __shfl_xor(acc[j], 16);
        acc[j] += __shfl_xor(acc[j], 32);
    }

    if (g == 0) {
        uint4 o;
        o.x = f2bf(acc[0] * dv) | (f2bf(acc[1] * dv) << 16);
        o.y = f2bf(acc[2] * dv) | (f2bf(acc[3] * dv) << 16);
        o.z = f2bf(acc[4] * dv) | (f2bf(acc[5] * dv) << 16);
        o.w = f2bf(acc[6] * dv) | (f2bf(acc[7] * dv) << 16);
        *(uint4*)(O + (size_t)node * DIN + li * 8) = o;
    }
}

// ---------------- bf16 MFMA GEMM: out[M][256] = A[M][K] * Bt[256][K]^T + bias
// Fused colsum/colsumsq -> per-block partials (no global atomics).
template <int K, int OUTB>
__global__ __launch_bounds__(256) void gemm_bf16(
    const u16* __restrict__ A, const u16* __restrict__ Bt,
    const float* __restrict__ bias, void* __restrict__ outp,
    float* __restrict__ part, int M)
{
    __shared__ __align__(16) u16 lA[4096];
    __shared__ __align__(16) u16 lB[4096];
    __shared__ float red[256];
    const int tid = threadIdx.x;
    const int lane = tid & 63;
    const int wid = tid >> 6;
    const int wm = wid >> 1, wn = wid & 1;
    const int l15 = lane & 15, khi = lane >> 4;
    const int row0 = blockIdx.x * 128;
    const int col0 = blockIdx.y * 128;

    f32x4 acc[4][4];
#pragma unroll
    for (int i = 0; i < 4; ++i)
#pragma unroll
        for (int j = 0; j < 4; ++j)
            acc[i][j] = (f32x4){0.f, 0.f, 0.f, 0.f};

    if (tid < 256) red[tid] = 0.f;

    for (int k0 = 0; k0 < K; k0 += 32) {
#pragma unroll
        for (int t = 0; t < 2; ++t) {
            int c = t * 256 + wid * 64 + lane;
            int r = c & 127, kh = c >> 7;
            int ar = row0 + r; if (ar > M - 1) ar = M - 1;
            const u16* ga = A + (size_t)ar * K + k0 + kh * 8;
            u16* la = &lA[(t * 256 + wid * 64) * 8];
            __builtin_amdgcn_global_load_lds(
                (const __attribute__((address_space(1))) void*)ga,
                (__attribute__((address_space(3))) void*)la, 16, 0, 0);
            const u16* gb = Bt + (size_t)(col0 + r) * K + k0 + kh * 8;
            u16* lb = &lB[(t * 256 + wid * 64) * 8];
            __builtin_amdgcn_global_load_lds(
                (const __attribute__((address_space(1))) void*)gb,
                (__attribute__((address_space(3))) void*)lb, 16, 0, 0);
        }
        __syncthreads();
        bf16x8 afr[4], bfr[4];
#pragma unroll
        for (int mi = 0; mi < 4; ++mi)
            afr[mi] = *(const bf16x8*)&lA[khi * 1024 + (wm * 64 + mi * 16 + l15) * 8];
#pragma unroll
        for (int nj = 0; nj < 4; ++nj)
            bfr[nj] = *(const bf16x8*)&lB[khi * 1024 + (wn * 64 + nj * 16 + l15) * 8];
#pragma unroll
        for (int mi = 0; mi < 4; ++mi)
#pragma unroll
            for (int nj = 0; nj < 4; ++nj)
                acc[mi][nj] = __builtin_amdgcn_mfma_f32_16x16x32_bf16(
                    afr[mi], bfr[nj], acc[mi][nj], 0, 0, 0);
        __syncthreads();
    }

#pragma unroll
    for (int mi = 0; mi < 4; ++mi) {
#pragma unroll
        for (int nj = 0; nj < 4; ++nj) {
            int coll = wn * 64 + nj * 16 + l15;
            int colg = col0 + coll;
            float bsv = bias[colg];
            float s = 0.f, q = 0.f;
#pragma unroll
            for (int i = 0; i < 4; ++i) {
                int rowg = row0 + wm * 64 + mi * 16 + khi * 4 + i;
                if (rowg < M) {
                    float v = acc[mi][nj][i] + bsv;
                    if (OUTB) ((u16*)outp)[(size_t)rowg * 256 + colg] = (u16)f2bf(v);
                    else      ((float*)outp)[(size_t)rowg * 256 + colg] = v;
                    s += v; q += v * v;
                }
            }
            s += __shfl_xor(s, 16); s += __shfl_xor(s, 32);
            q += __shfl_xor(q, 16); q += __shfl_xor(q, 32);
            if (lane < 16) {
                atomicAdd(&red[coll * 2], s);
                atomicAdd(&red[coll * 2 + 1], q);
            }
        }
    }
    __syncthreads();
    if (tid < 256)
        part[(size_t)blockIdx.x * 512 + blockIdx.y * 256 + tid] = red[tid];
}

// ---------------- BN stats: one WAVE per channel reduces partials ----------------
__global__ __launch_bounds__(256) void bn_stats_k(
    const float* __restrict__ part, const float* __restrict__ gamma,
    const float* __restrict__ beta, float* __restrict__ ss, int nbx, int M)
{
    int wave = threadIdx.x >> 6;
    int lane = threadIdx.x & 63;
    int c = blockIdx.x * 4 + wave; // 0..255
    int base = (c >> 7) * 256 + (c & 127) * 2;
    float s = 0.f, q = 0.f;
    for (int bx = lane; bx < nbx; bx += 64) {
        float2 v = *(const float2*)&part[(size_t)bx * 512 + base];
        s += v.x; q += v.y;
    }
#pragma unroll
    for (int m = 32; m >= 1; m >>= 1) {
        s += __shfl_xor(s, m);
        q += __shfl_xor(q, m);
    }
    if (lane == 0) {
        float mean = s / (float)M;
        float var = fmaxf(q / (float)M - mean * mean, 0.f);
        float sc = gamma[c] * rsqrtf(var + BN_EPS);
        ss[c] = sc;
        ss[256 + c] = beta[c] - mean * sc;
    }
}

// ---------------- BN apply + PReLU ----------------
template <int INB, int OUTB> // bf16 flags for input/output
__global__ void bn_prelu_k(const void* __restrict__ in, void* __restrict__ outp,
                           const float* __restrict__ ss,
                           const float* __restrict__ aptr, int nquads) {
    float a = aptr[0];
    int i = blockIdx.x * blockDim.x + threadIdx.x;
    int stride = gridDim.x * blockDim.x;
    for (; i < nquads; i += stride) {
        float v0, v1, v2, v3;
        if (INB) {
            uint2 u = ((const uint2*)in)[i];
            v0 = bflo(u.x); v1 = bfhi(u.x); v2 = bflo(u.y); v3 = bfhi(u.y);
        } else {
            float4 v = ((const float4*)in)[i];
            v0 = v.x; v1 = v.y; v2 = v.z; v3 = v.w;
        }
        int c0 = (i * 4) & 255;
        float r0 = v0 * ss[c0 + 0] + ss[256 + c0 + 0];
        float r1 = v1 * ss[c0 + 1] + ss[256 + c0 + 1];
        float r2 = v2 * ss[c0 + 2] + ss[256 + c0 + 2];
        float r3 = v3 * ss[c0 + 3] + ss[256 + c0 + 3];
        r0 = r0 > 0.f ? r0 : a * r0;
        r1 = r1 > 0.f ? r1 : a * r1;
        r2 = r2 > 0.f ? r2 : a * r2;
        r3 = r3 > 0.f ? r3 : a * r3;
        if (OUTB) {
            u32 lo = f2bf(r0) | (f2bf(r1) << 16);
            u32 hi = f2bf(r2) | (f2bf(r3) << 16);
            ((uint2*)outp)[i] = make_uint2(lo, hi);
        } else {
            ((float4*)outp)[i] = make_float4(r0, r1, r2, r3);
        }
    }
}

extern "C" void kernel_launch(void* const* d_in, const int* in_sizes, int n_in,
                              void* d_out, int out_size, void* d_ws, size_t ws_size,
                              hipStream_t stream) {
    const float* x   = (const float*)d_in[0];
    const void*  ei  = d_in[1];
    const float* W0  = (const float*)d_in[2];
    const float* b0  = (const float*)d_in[3];
    const float* g0  = (const float*)d_in[4];
    const float* be0 = (const float*)d_in[5];
    const float* a0  = (const float*)d_in[6];
    const float* W1  = (const float*)d_in[7];
    const float* b1  = (const float*)d_in[8];
    const float* g1  = (const float*)d_in[9];
    const float* be1 = (const float*)d_in[10];
    const float* a1  = (const float*)d_in[11];
    float* out = (float*)d_out;

    const int n = in_sizes[0] / 128;
    const int E = in_sizes[1] / 2;
    const int nbx = (n + 127) / 128;

    char* ws = (char*)d_ws;
    size_t off = 0;
    auto alloc = [&](size_t bytes) {
        size_t r = off; off += (bytes + 255) & ~(size_t)255; return r;
    };
    size_t o_deg  = alloc((size_t)n * 4);
    size_t o_fill = alloc((size_t)n * 4);
    size_t o_rp   = alloc((size_t)(n + 1) * 4);
    size_t o_bsum = alloc(4096);
    size_t o_flag = alloc(256);
    size_t o_dinv = alloc((size_t)n * 4);
    size_t o_csr  = alloc((size_t)E * 8);       // uint2 {src, dinv[src]}
    size_t o_part = alloc((size_t)nbx * 512 * 4);
    size_t o_ss   = alloc(2048);
    size_t o_wt0  = alloc(256 * 128 * 2);
    size_t o_wt1  = alloc(256 * 256 * 2);
    size_t o_xh   = alloc((size_t)n * 128 * 2);
    size_t o_agg0 = alloc((size_t)n * 128 * 2);
    size_t o_y0   = alloc((size_t)n * 256 * 2);
    size_t o_agg1 = o_xh; // overlay: xh+agg0 dead by the time agg1 is written

    int*   degi  = (int*)(ws + o_deg);
    int*   fill  = (int*)(ws + o_fill);
    int*   rp    = (int*)(ws + o_rp);
    int*   bsum  = (int*)(ws + o_bsum);
    int*   flag  = (int*)(ws + o_flag);
    float* dinv  = (float*)(ws + o_dinv);
    uint2* csrv  = (uint2*)(ws + o_csr);
    float* part  = (float*)(ws + o_part);
    float* ssbuf = (float*)(ws + o_ss);
    u16*   wt0   = (u16*)(ws + o_wt0);
    u16*   wt1   = (u16*)(ws + o_wt1);
    u16*   xh    = (u16*)(ws + o_xh);
    u16*   agg0  = (u16*)(ws + o_agg0);
    u16*   y0    = (u16*)(ws + o_y0);
    u16*   agg1  = (u16*)(ws + o_agg1);

    hipMemsetAsync(ws + o_deg, 0, (size_t)n * 4, stream);
    hipMemsetAsync(ws + o_fill, 0, (size_t)n * 4, stream);

    const int gE = (E + 255) / 256 < 4096 ? (E + 255) / 256 : 4096;
    const int gN = (n + 255) / 256;

    detect_k<<<1, 64, 0, stream>>>(ei, flag, n);
    deg_count_k<<<gE, 256, 0, stream>>>(ei, flag, degi, E);
    dinv_k<<<gN, 256, 0, stream>>>(degi, dinv, n);
    block_sum_k<<<gN, 256, 0, stream>>>(degi, bsum, n);
    scan_bsum_k<<<1, 256, 0, stream>>>(bsum, gN);
    block_scan_k<<<gN, 256, 0, stream>>>(degi, bsum, rp, n);
    csr_fill_k<<<gE, 256, 0, stream>>>(ei, flag, dinv, rp, fill, csrv, E);

    f32_to_bf16_k<<<4096, 256, 0, stream>>>(x, xh, n * 128 / 4);
    transpose_w_k<<<(128 * 256 + 255) / 256, 256, 0, stream>>>(W0, wt0, 128, 256);
    transpose_w_k<<<(256 * 256 + 255) / 256, 256, 0, stream>>>(W1, wt1, 256, 256);

    const dim3 ggrid(nbx, 2);

    // ---- layer 0 ----  (pre-BN bf16 into d_out scratch)
    aggregate_k<128><<<(n + 3) / 4, 256, 0, stream>>>(xh, agg0, dinv, rp, csrv, n);
    gemm_bf16<128, 1><<<ggrid, 256, 0, stream>>>(agg0, wt0, b0, d_out, part, n);
    bn_stats_k<<<64, 256, 0, stream>>>(part, g0, be0, ssbuf, nbx, n);
    bn_prelu_k<1, 1><<<4096, 256, 0, stream>>>(d_out, y0, ssbuf, a0, n * 256 / 4);

    // ---- layer 1 ----  (pre-BN bf16 into y0 — dead after aggregate; final f32 to d_out)
    aggregate_k<256><<<(n + 3) / 4, 256, 0, stream>>>(y0, agg1, dinv, rp, csrv, n);
    gemm_bf16<256, 1><<<ggrid, 256, 0, stream>>>(agg1, wt1, b1, y0, part, n);
    bn_stats_k<<<64, 256, 0, stream>>>(part, g1, be1, ssbuf, nbx, n);
    bn_prelu_k<1, 0><<<4096, 256, 0, stream>>>(y0, out, ssbuf, a1, n * 256 / 4);
}